// Round 6
// baseline (1573.832 us; speedup 1.0000x reference)
//
#include <hip/hip_runtime.h>
#include <hip/hip_bf16.h>

typedef __attribute__((ext_vector_type(8))) short bfrag_t;   // 8 bf16 (4 VGPRs)
typedef __attribute__((ext_vector_type(4))) float accum_t;   // 4 f32

static_assert(sizeof(bfrag_t) == 16, "frag size");

static constexpr int M_NODES = 50000;
static constexpr int E_EDGES = 156000;
static constexpr int D       = 512;
static constexpr int MT      = (M_NODES + 127) / 128;  // 391 M-tiles
static constexpr int NT      = 4;                      // 512/128 N-tiles
static constexpr int NWG     = MT * NT;                // 1564
static constexpr int XQ      = NWG / 8;                // 195
static constexpr int XR      = NWG % 8;                // 4

// ---- manual RNE f32 -> bf16 ----
__device__ __forceinline__ unsigned short f2bf(float f) {
  unsigned int u = __float_as_uint(f);
  u = (u + 0x7FFFu + ((u >> 16) & 1u)) >> 16;
  return (unsigned short)u;
}

// ---------------- weight cast + transpose: Wt[mat][n][k] = bf16(W[mat][k][n]) ----
__global__ void cast_w_kernel(const float* __restrict__ Wself,
                              const float* __restrict__ W1,
                              const float* __restrict__ W2,
                              unsigned short* __restrict__ Wt) {
  int idx = blockIdx.x * 256 + threadIdx.x;
  if (idx >= 7 * 262144) return;
  int mat = idx >> 18;
  int rem = idx & 262143;
  int k = rem >> 9;
  int n = rem & 511;
  float v;
  if (mat == 0)      v = Wself[rem];
  else if (mat <= 3) v = W1[(size_t)(mat - 1) * 262144 + rem];
  else               v = W2[(size_t)(mat - 4) * 262144 + rem];
  Wt[(size_t)mat * 262144 + (size_t)n * 512 + k] = f2bf(v);
}

// ---------------- h = bf16(x [+ agg]) ----------------
template <bool USE_AGG>
__global__ void build_h_kernel(const float* __restrict__ x,
                               const float* __restrict__ agg,
                               unsigned short* __restrict__ h, int n) {
  int stride = gridDim.x * blockDim.x;
  int n4 = n >> 2;
  for (int i = blockIdx.x * blockDim.x + threadIdx.x; i < n4; i += stride) {
    float4 v = ((const float4*)x)[i];
    if (USE_AGG) {
      float4 a = ((const float4*)agg)[i];
      v.x += a.x; v.y += a.y; v.z += a.z; v.w += a.w;
    }
    ushort4 u;
    u.x = f2bf(v.x); u.y = f2bf(v.y); u.z = f2bf(v.z); u.w = f2bf(v.w);
    ((ushort4*)h)[i] = u;
  }
}

// ---------------- scatter: agg[dst] += x[src] for edges of type rel ----------
__global__ void scatter_kernel(const float* __restrict__ x,
                               const int* __restrict__ ei,
                               const int* __restrict__ et,
                               int rel, float* __restrict__ agg) {
  int e    = blockIdx.x * 4 + (threadIdx.x >> 6);
  int lane = threadIdx.x & 63;
  if (e >= E_EDGES) return;
  if (et[e] != rel) return;
  int src = ei[e];
  int dst = ei[E_EDGES + e];
  const float* xs = x + (size_t)src * D;
  float* ad = agg + (size_t)dst * D;
  float v[8];
#pragma unroll
  for (int j = 0; j < 8; ++j) v[j] = xs[j * 64 + lane];
#pragma unroll
  for (int j = 0; j < 8; ++j) unsafeAtomicAdd(ad + j * 64 + lane, v[j]);
}

// ---------------- GEMM: C[M,512] = A[M,512](bf16) @ B[512,512] + bias --------
// Barrier-free, LDS-free: each wave owns a 64x64 output tile and streams A/B
// fragments straight from global (L1/L2) into VGPRs; 2-deep register double
// buffer; latency hidden purely by wave-level TLP (no lockstep sync points).
// MODE 0: f32 store. 1: relu->bf16. 2: f32 RMW accumulate.
template <int MODE>
__global__ __launch_bounds__(256, 3) void gemm_kernel(
    const unsigned short* __restrict__ A,
    const unsigned short* __restrict__ Bt,
    const float* __restrict__ bias,
    float* __restrict__ outF,
    unsigned short* __restrict__ outB) {
  const int tid  = threadIdx.x;
  const int lane = tid & 63;
  const int wid  = tid >> 6;
  const int wm   = wid >> 1;   // 0..1 : 64-row band within 128
  const int wn   = wid & 1;    // 0..1 : 64-col band within 128

  // T1: bijective XCD-chunked swizzle (m204). Consecutive swz share an A-tile.
  const int orig = blockIdx.x;
  const int xcd  = orig & 7;
  const int lid  = orig >> 3;
  const int swz  = (xcd < XR ? xcd * (XQ + 1) : XR * (XQ + 1) + (xcd - XR) * XQ) + lid;
  const int tileM = (swz >> 2) * 128;
  const int tileN = (swz & 3) * 128;

  const int fr  = lane & 15;   // row (A) / col (B) within 16x16 fragment
  const int kcl = lane >> 4;   // 8-wide k-chunk within the 32-k step

  // Per-fragment base pointers; all K offsets (ks*64B, max 960B) fold into the
  // 13-bit signed instruction offset -> zero address arithmetic in the loop.
  const unsigned short* pa[4];
  const unsigned short* pb[4];
#pragma unroll
  for (int m = 0; m < 4; ++m) {
    int row = tileM + wm * 64 + m * 16 + fr;
    row = row < M_NODES ? row : M_NODES - 1;
    pa[m] = A + (size_t)row * D + kcl * 8;
  }
#pragma unroll
  for (int n = 0; n < 4; ++n)
    pb[n] = Bt + (size_t)(tileN + wn * 64 + n * 16 + fr) * D + kcl * 8;

  accum_t acc[4][4] = {};
  bfrag_t a0[4], b0[4], a1[4], b1[4];

#define LD(aa, bb, ks)                                               \
  do {                                                               \
    _Pragma("unroll") for (int m = 0; m < 4; ++m)                    \
        aa[m] = *(const bfrag_t*)(pa[m] + (ks) * 32);                \
    _Pragma("unroll") for (int n = 0; n < 4; ++n)                    \
        bb[n] = *(const bfrag_t*)(pb[n] + (ks) * 32);                \
  } while (0)
#define FM(aa, bb)                                                   \
  do {                                                               \
    _Pragma("unroll") for (int m = 0; m < 4; ++m)                    \
      _Pragma("unroll") for (int n = 0; n < 4; ++n)                  \
        acc[m][n] = __builtin_amdgcn_mfma_f32_16x16x32_bf16(         \
            aa[m], bb[n], acc[m][n], 0, 0, 0);                       \
  } while (0)

  LD(a0, b0, 0);
#pragma unroll
  for (int ks = 0; ks < 16; ks += 2) {
    LD(a1, b1, ks + 1);      // prefetch odd step while even step computes
    FM(a0, b0);
    if (ks + 2 < 16) LD(a0, b0, ks + 2);  // prefetch next even step
    FM(a1, b1);
  }
#undef LD
#undef FM

  // epilogue: C row = (lane>>4)*4 + q, col = lane&15 (m89-verified layout)
  const int rq = lane >> 4;
#pragma unroll
  for (int n = 0; n < 4; ++n) {
    const int col = tileN + wn * 64 + n * 16 + fr;
    const float bv = bias[col];
#pragma unroll
    for (int m = 0; m < 4; ++m) {
      const int rbase = tileM + wm * 64 + m * 16 + rq * 4;
#pragma unroll
      for (int q = 0; q < 4; ++q) {
        const int row = rbase + q;
        if (row < M_NODES) {
          float v = acc[m][n][q] + bv;
          const size_t idx = (size_t)row * D + col;
          if (MODE == 0)      outF[idx] = v;
          else if (MODE == 1) outB[idx] = f2bf(fmaxf(v, 0.f));
          else                outF[idx] += v;
        }
      }
    }
  }
}

extern "C" void kernel_launch(void* const* d_in, const int* in_sizes, int n_in,
                              void* d_out, int out_size, void* d_ws, size_t ws_size,
                              hipStream_t stream) {
  const float* x     = (const float*)d_in[0];
  const int*   ei    = (const int*)d_in[1];
  const int*   et    = (const int*)d_in[2];
  const float* Wself = (const float*)d_in[3];
  const float* bself = (const float*)d_in[4];
  const float* W1    = (const float*)d_in[5];
  const float* b1    = (const float*)d_in[6];
  const float* W2    = (const float*)d_in[7];
  const float* b2    = (const float*)d_in[8];
  float* out = (float*)d_out;

  char* ws = (char*)d_ws;
  unsigned short* h   = (unsigned short*)ws;               // 51.2 MB  bf16 A operand
  float*          agg = (float*)(ws + 51200000);           // 102.4 MB fp32 segment-sum
  unsigned short* mid = (unsigned short*)(ws + 51200000);  // aliases agg (51.2 MB bf16)
  unsigned short* Wt  = (unsigned short*)(ws + 153600000); // 3.67 MB  bf16 W^T x7

  cast_w_kernel<<<7 * 1024, 256, 0, stream>>>(Wself, W1, W2, Wt);
  build_h_kernel<false><<<2048, 256, 0, stream>>>(x, nullptr, h, M_NODES * D);
  gemm_kernel<0><<<NWG, 256, 0, stream>>>(h, Wt, bself, out, nullptr);

  for (int r = 0; r < 3; ++r) {
    hipMemsetAsync(agg, 0, (size_t)M_NODES * D * sizeof(float), stream);
    scatter_kernel<<<(E_EDGES + 3) / 4, 256, 0, stream>>>(x, ei, et, r, agg);
    build_h_kernel<true><<<2048, 256, 0, stream>>>(x, agg, h, M_NODES * D);
    gemm_kernel<1><<<NWG, 256, 0, stream>>>(h, Wt + (size_t)(1 + r) * 262144,
                                            b1 + (size_t)r * 512, nullptr, mid);
    gemm_kernel<2><<<NWG, 256, 0, stream>>>(mid, Wt + (size_t)(4 + r) * 262144,
                                            b2 + (size_t)r * 512, out, nullptr);
  }
}

// Round 7
// 1070.920 us; speedup vs baseline: 1.4696x; 1.4696x over previous
//
#include <hip/hip_runtime.h>
#include <hip/hip_bf16.h>

typedef __attribute__((ext_vector_type(8))) short bfrag_t;   // 8 bf16 (4 VGPRs)
typedef __attribute__((ext_vector_type(4))) float accum_t;   // 4 f32

static_assert(sizeof(bfrag_t) == 16, "frag size");

static constexpr int M_NODES = 50000;
static constexpr int E_EDGES = 156000;
static constexpr int MT      = (M_NODES + 127) / 128;  // 391 M-tiles

// ---- manual RNE f32 -> bf16 ----
__device__ __forceinline__ unsigned short f2bf(float f) {
  unsigned int u = __float_as_uint(f);
  u = (u + 0x7FFFu + ((u >> 16) & 1u)) >> 16;
  return (unsigned short)u;
}
__device__ __forceinline__ float bf2f(unsigned short u) {
  return __uint_as_float(((unsigned int)u) << 16);
}

__device__ __forceinline__ void gll16(const unsigned short* g, unsigned short* l) {
  __builtin_amdgcn_global_load_lds(
      (const __attribute__((address_space(1))) void*)g,
      (__attribute__((address_space(3))) void*)l,
      16, 0, 0);
}

// ---- weight prep:
//  Wt1[2048][512]: n<512 -> Wself^T ; n>=512 -> W1_r^T  (bf16, k-contiguous)
//  Wt2[512][1536]: Wt2[n][r*512+c] = W2[r][c][n]        (bf16, k-contiguous)
//  bias2[512] = sum_r b2[r]
__global__ void cast_w_kernel(const float* __restrict__ Wself,
                              const float* __restrict__ W1,
                              const float* __restrict__ W2,
                              const float* __restrict__ b2,
                              unsigned short* __restrict__ Wt1,
                              unsigned short* __restrict__ Wt2,
                              float* __restrict__ bias2) {
  int idx = blockIdx.x * 256 + threadIdx.x;
  if (idx < 1048576) {                       // Wt1
    int n = idx >> 9, k = idx & 511;
    float v = (n < 512)
        ? Wself[k * 512 + n]
        : W1[(size_t)((n - 512) >> 9) * 262144 + k * 512 + ((n - 512) & 511)];
    Wt1[idx] = f2bf(v);
  } else if (idx < 1835008) {                // Wt2 (j = n*1536 + kk)
    int j = idx - 1048576;
    int kk = j % 1536;
    int n  = j / 1536;
    Wt2[j] = f2bf(W2[(size_t)(kk >> 9) * 262144 + (size_t)(kk & 511) * 512 + n]);
  } else if (idx < 1835520) {                // bias2
    int c = idx - 1835008;
    bias2[c] = b2[c] + b2[512 + c] + b2[1024 + c];
  }
}

// ---- cast x (f32) -> xb (bf16), vectorized ----
__global__ void cast_x_kernel(const float* __restrict__ x,
                              unsigned short* __restrict__ xb, int n) {
  int stride = gridDim.x * blockDim.x;
  int n4 = n >> 2;
  for (int i = blockIdx.x * blockDim.x + threadIdx.x; i < n4; i += stride) {
    float4 v = ((const float4*)x)[i];
    ushort4 u;
    u.x = f2bf(v.x); u.y = f2bf(v.y); u.z = f2bf(v.z); u.w = f2bf(v.w);
    ((ushort4*)xb)[i] = u;
  }
}

// ---- scatter in output space: aggY[dst] += Ymlp[src, rel-cols] ----
// Coalesced: atomic j covers bytes [j*256, j*256+256) across 64 lanes.
__global__ void scatter_y_kernel(const unsigned short* __restrict__ ymlp,
                                 const int* __restrict__ ei,
                                 const int* __restrict__ et,
                                 int rel, float* __restrict__ aggY) {
  int e    = blockIdx.x * 4 + (threadIdx.x >> 6);
  int lane = threadIdx.x & 63;
  if (e >= E_EDGES) return;
  if (et[e] != rel) return;
  int src = ei[e];
  int dst = ei[E_EDGES + e];
  const unsigned short* zs = ymlp + (size_t)src * 1536 + rel * 512;
  float* ad = aggY + (size_t)dst * 512;
  float v[8];
#pragma unroll
  for (int j = 0; j < 8; ++j) v[j] = bf2f(zs[j * 64 + lane]);
#pragma unroll
  for (int j = 0; j < 8; ++j) unsafeAtomicAdd(ad + j * 64 + lane, v[j]);
}

// ---- in-place: Ymlp_r = relu(Ymlp_r + aggY + b1_r)  (bf16, elementwise) ----
__global__ void relu_h_kernel(unsigned short* __restrict__ ymlp,
                              const float* __restrict__ aggY,
                              const float* __restrict__ b1,  // [3*512]
                              int rel) {
  int i = blockIdx.x * 256 + threadIdx.x;   // one thread = 8 cols
  int row = i >> 6;
  int c8  = (i & 63) * 8;
  if (row >= M_NODES) return;
  unsigned short* p = ymlp + (size_t)row * 1536 + rel * 512 + c8;
  ushort4 lo = ((ushort4*)p)[0];
  ushort4 hi = ((ushort4*)p)[1];
  float4 a0 = *(const float4*)(aggY + (size_t)row * 512 + c8);
  float4 a1 = *(const float4*)(aggY + (size_t)row * 512 + c8 + 4);
  const float* bb = b1 + rel * 512 + c8;
  ushort4 o0, o1;
  o0.x = f2bf(fmaxf(bf2f(lo.x) + a0.x + bb[0], 0.f));
  o0.y = f2bf(fmaxf(bf2f(lo.y) + a0.y + bb[1], 0.f));
  o0.z = f2bf(fmaxf(bf2f(lo.z) + a0.z + bb[2], 0.f));
  o0.w = f2bf(fmaxf(bf2f(lo.w) + a0.w + bb[3], 0.f));
  o1.x = f2bf(fmaxf(bf2f(hi.x) + a1.x + bb[4], 0.f));
  o1.y = f2bf(fmaxf(bf2f(hi.y) + a1.y + bb[5], 0.f));
  o1.z = f2bf(fmaxf(bf2f(hi.z) + a1.z + bb[6], 0.f));
  o1.w = f2bf(fmaxf(bf2f(hi.w) + a1.w + bb[7], 0.f));
  ((ushort4*)p)[0] = o0;
  ((ushort4*)p)[1] = o1;
}

// ---------------- fused GEMM (R3-validated template, depth-1 dbuf) ----------
// C[M, NTC*128] = A[M,K](bf16) @ Bt[NTC*128, K]^T.
// MODE 1 (expand): col<512 -> outF[row*512+col] = acc + biasF[col] (f32)
//                  col>=512 -> outB[row*1536+col-512] = bf16(acc)   (no bias!)
// MODE 2 (reduce): outF[row*512+col] += acc + biasF[col]            (f32 RMW)
template <int NTC, int MODE>
__global__ __launch_bounds__(256) void gemm_kernel(
    const unsigned short* __restrict__ A,
    const unsigned short* __restrict__ Bt,
    int K,
    float* __restrict__ outF,
    unsigned short* __restrict__ outB,
    const float* __restrict__ biasF) {
  __shared__ alignas(16) unsigned short As[2][4096];  // [buf][kc][row][8]
  __shared__ alignas(16) unsigned short Bs[2][4096];
  const int tid  = threadIdx.x;
  const int lane = tid & 63;
  const int wid  = tid >> 6;
  const int wr   = wid >> 1;
  const int wc   = wid & 1;

  // T1: bijective XCD-chunked swizzle (m204), general form.
  constexpr int nwg = MT * NTC;
  constexpr int q   = nwg / 8;
  constexpr int rr  = nwg % 8;
  const int orig = blockIdx.x;
  const int xcd  = orig & 7;
  const int lid  = orig >> 3;
  const int swz  = (xcd < rr ? xcd * (q + 1) : rr * (q + 1) + (xcd - rr) * q) + lid;
  const int tileM = (swz / NTC) * 128;
  const int tileN = (swz % NTC) * 128;

  accum_t acc[4][4] = {};

  const int t0 = tid, t1 = tid + 256;
  const int kc0 = t0 >> 7, r0 = t0 & 127;
  const int kc1 = t1 >> 7, r1 = t1 & 127;
  int ar0 = tileM + r0; ar0 = ar0 < M_NODES ? ar0 : M_NODES - 1;
  int ar1 = tileM + r1; ar1 = ar1 < M_NODES ? ar1 : M_NODES - 1;
  const unsigned short* gA0 = A + (size_t)ar0 * K + kc0 * 8;
  const unsigned short* gA1 = A + (size_t)ar1 * K + kc1 * 8;
  const unsigned short* gB0 = Bt + (size_t)(tileN + r0) * K + kc0 * 8;
  const unsigned short* gB1 = Bt + (size_t)(tileN + r1) * K + kc1 * 8;

  const int kcl = lane >> 4;
  const int fr  = lane & 15;
  const unsigned short* pAf = &As[0][kcl * 1024 + (wr * 64 + fr) * 8];
  const unsigned short* pBf = &Bs[0][kcl * 1024 + (wc * 64 + fr) * 8];

#define STAGE(b, ks)                                  \
  do {                                                \
    const int koff_ = (ks) * 32;                      \
    gll16(gA0 + koff_, &As[(b)][t0 * 8]);             \
    gll16(gA1 + koff_, &As[(b)][t1 * 8]);             \
    gll16(gB0 + koff_, &Bs[(b)][t0 * 8]);             \
    gll16(gB1 + koff_, &Bs[(b)][t1 * 8]);             \
  } while (0)

  const int ksteps = K >> 5;
  STAGE(0, 0);
  for (int ks = 0; ks < ksteps; ++ks) {
    const int cur = ks & 1;
    if (ks + 1 < ksteps) {
      STAGE(cur ^ 1, ks + 1);                           // prefetch next tile
      asm volatile("s_waitcnt vmcnt(4)" ::: "memory");  // wait current only
    } else {
      asm volatile("s_waitcnt vmcnt(0)" ::: "memory");
    }
    __builtin_amdgcn_s_barrier();

    bfrag_t a[4], b[4];
    const unsigned short* pA = pAf + cur * 4096;
    const unsigned short* pB = pBf + cur * 4096;
#pragma unroll
    for (int m = 0; m < 4; ++m) a[m] = *(const bfrag_t*)(pA + m * 16 * 8);
#pragma unroll
    for (int n = 0; n < 4; ++n) b[n] = *(const bfrag_t*)(pB + n * 16 * 8);
    __builtin_amdgcn_s_setprio(1);
#pragma unroll
    for (int m = 0; m < 4; ++m)
#pragma unroll
      for (int n = 0; n < 4; ++n)
        acc[m][n] = __builtin_amdgcn_mfma_f32_16x16x32_bf16(a[m], b[n], acc[m][n], 0, 0, 0);
    __builtin_amdgcn_s_setprio(0);
    __builtin_amdgcn_s_barrier();
  }
#undef STAGE

  // epilogue: C row = (lane>>4)*4 + q, col = lane&15 (m89-verified layout)
  const int rq = lane >> 4;
#pragma unroll
  for (int n = 0; n < 4; ++n) {
    const int col = tileN + wc * 64 + n * 16 + fr;
    const float bv = (MODE == 2 || col < 512) ? biasF[col & 511] : 0.f;
#pragma unroll
    for (int m = 0; m < 4; ++m) {
      const int rbase = tileM + wr * 64 + m * 16 + rq * 4;
#pragma unroll
      for (int p = 0; p < 4; ++p) {
        const int row = rbase + p;
        if (row < M_NODES) {
          float v = acc[m][n][p] + bv;
          if (MODE == 1) {
            if (col < 512) outF[(size_t)row * 512 + col] = v;
            else           outB[(size_t)row * 1536 + (col - 512)] = f2bf(v);
          } else {
            outF[(size_t)row * 512 + col] += v;
          }
        }
      }
    }
  }
}

extern "C" void kernel_launch(void* const* d_in, const int* in_sizes, int n_in,
                              void* d_out, int out_size, void* d_ws, size_t ws_size,
                              hipStream_t stream) {
  const float* x     = (const float*)d_in[0];
  const int*   ei    = (const int*)d_in[1];
  const int*   et    = (const int*)d_in[2];
  const float* Wself = (const float*)d_in[3];
  const float* bself = (const float*)d_in[4];
  const float* W1    = (const float*)d_in[5];
  const float* b1    = (const float*)d_in[6];
  const float* W2    = (const float*)d_in[7];
  const float* b2    = (const float*)d_in[8];
  float* out = (float*)d_out;

  char* ws = (char*)d_ws;
  unsigned short* xb    = (unsigned short*)ws;                 // 51.2 MB bf16 x
  unsigned short* ymlp  = (unsigned short*)(ws + 51200000);    // 153.6 MB bf16 [M,1536]
  float*          aggY  = (float*)(ws + 204800000);            // 102.4 MB f32 [M,512]
  unsigned short* Wt1   = (unsigned short*)(ws + 307200000);   // 2.1 MB
  unsigned short* Wt2   = (unsigned short*)(ws + 309297152);   // 1.6 MB
  float*          bias2 = (float*)(ws + 310870016);            // 2 KB

  cast_w_kernel<<<7171, 256, 0, stream>>>(Wself, W1, W2, b2, Wt1, Wt2, bias2);
  cast_x_kernel<<<2048, 256, 0, stream>>>(x, xb, M_NODES * 512);

  // Y = x @ [W_self | W1_0 | W1_1 | W1_2] ; cols<512 -> out(f32)+b_self,
  // cols>=512 -> ymlp(bf16, NO b1: b1 must not enter the segment-sum)
  gemm_kernel<16, 1><<<MT * 16, 256, 0, stream>>>(xb, Wt1, 512, out, ymlp, bself);

  for (int r = 0; r < 3; ++r) {
    hipMemsetAsync(aggY, 0, (size_t)M_NODES * 512 * sizeof(float), stream);
    scatter_y_kernel<<<E_EDGES / 4, 256, 0, stream>>>(ymlp, ei, et, r, aggY);
    relu_h_kernel<<<M_NODES * 64 / 256, 256, 0, stream>>>(ymlp, aggY, b1, r);
  }

  // out += [h0|h1|h2] @ [W2_0; W2_1; W2_2] + bias2
  gemm_kernel<4, 2><<<MT * 4, 256, 0, stream>>>(ymlp, Wt2, 1536, out, nullptr, bias2);
}

// Round 8
// 885.852 us; speedup vs baseline: 1.7766x; 1.2089x over previous
//
#include <hip/hip_runtime.h>
#include <hip/hip_bf16.h>

typedef __attribute__((ext_vector_type(8))) short bfrag_t;   // 8 bf16 (4 VGPRs)
typedef __attribute__((ext_vector_type(4))) float accum_t;   // 4 f32
typedef __attribute__((ext_vector_type(8))) unsigned short us8_t;

static_assert(sizeof(bfrag_t) == 16, "frag size");

static constexpr int M_NODES = 50000;
static constexpr int E_EDGES = 156000;
static constexpr int MT      = (M_NODES + 127) / 128;  // 391 M-tiles

// ---- manual RNE f32 -> bf16 ----
__device__ __forceinline__ unsigned short f2bf(float f) {
  unsigned int u = __float_as_uint(f);
  u = (u + 0x7FFFu + ((u >> 16) & 1u)) >> 16;
  return (unsigned short)u;
}
__device__ __forceinline__ float bf2f(unsigned short u) {
  return __uint_as_float(((unsigned int)u) << 16);
}

__device__ __forceinline__ void gll16(const unsigned short* g, unsigned short* l) {
  __builtin_amdgcn_global_load_lds(
      (const __attribute__((address_space(1))) void*)g,
      (__attribute__((address_space(3))) void*)l,
      16, 0, 0);
}

// ---- packed bf16x2 atomic add (HW instruction if available, CAS fallback) ----
typedef __attribute__((ext_vector_type(2))) short s2v;
__device__ __forceinline__ void agg_atomic_add(unsigned int* p, unsigned int zv) {
#if __has_builtin(__builtin_amdgcn_global_atomic_fadd_v2bf16)
  s2v v;
  __builtin_memcpy(&v, &zv, 4);
  __builtin_amdgcn_global_atomic_fadd_v2bf16(
      (__attribute__((address_space(1))) s2v*)p, v);
#else
  unsigned int old = *p, assumed;
  do {
    assumed = old;
    float lo = bf2f((unsigned short)(assumed & 0xffffu)) +
               bf2f((unsigned short)(zv & 0xffffu));
    float hi = bf2f((unsigned short)(assumed >> 16)) +
               bf2f((unsigned short)(zv >> 16));
    unsigned int nv = (unsigned int)f2bf(lo) | ((unsigned int)f2bf(hi) << 16);
    old = atomicCAS(p, assumed, nv);
  } while (old != assumed);
#endif
}

// ---- weight prep:
//  Wt1[2048][512]: n<512 -> Wself^T ; n>=512 -> W1_r^T  (bf16, k-contiguous)
//  Wt2[512][1536]: Wt2[n][r*512+c] = W2[r][c][n]        (bf16, k-contiguous)
//  bias2[512] = sum_r b2[r]
__global__ void cast_w_kernel(const float* __restrict__ Wself,
                              const float* __restrict__ W1,
                              const float* __restrict__ W2,
                              const float* __restrict__ b2,
                              unsigned short* __restrict__ Wt1,
                              unsigned short* __restrict__ Wt2,
                              float* __restrict__ bias2) {
  int idx = blockIdx.x * 256 + threadIdx.x;
  if (idx < 1048576) {                       // Wt1
    int n = idx >> 9, k = idx & 511;
    float v = (n < 512)
        ? Wself[k * 512 + n]
        : W1[(size_t)((n - 512) >> 9) * 262144 + k * 512 + ((n - 512) & 511)];
    Wt1[idx] = f2bf(v);
  } else if (idx < 1835008) {                // Wt2 (j = n*1536 + kk)
    int j = idx - 1048576;
    int kk = j % 1536;
    int n  = j / 1536;
    Wt2[j] = f2bf(W2[(size_t)(kk >> 9) * 262144 + (size_t)(kk & 511) * 512 + n]);
  } else if (idx < 1835520) {                // bias2
    int c = idx - 1835008;
    bias2[c] = b2[c] + b2[512 + c] + b2[1024 + c];
  }
}

// ---- cast x (f32) -> xb (bf16), vectorized ----
__global__ void cast_x_kernel(const float* __restrict__ x,
                              unsigned short* __restrict__ xb, int n) {
  int stride = gridDim.x * blockDim.x;
  int n4 = n >> 2;
  for (int i = blockIdx.x * blockDim.x + threadIdx.x; i < n4; i += stride) {
    float4 v = ((const float4*)x)[i];
    ushort4 u;
    u.x = f2bf(v.x); u.y = f2bf(v.y); u.z = f2bf(v.z); u.w = f2bf(v.w);
    ((ushort4*)xb)[i] = u;
  }
}

// ---- fused scatter, ALL relations in one pass over the edge list ----
// agg[dst, rel*512+c] += Z[src, rel*512+c]  via packed bf16x2 atomics.
// Coalesced: atomic j covers 256 contiguous bytes across the 64 lanes.
__global__ void scatter_all_kernel(const unsigned short* __restrict__ Z,
                                   const int* __restrict__ ei,
                                   const int* __restrict__ et,
                                   unsigned short* __restrict__ agg) {
  int e    = blockIdx.x * 4 + (threadIdx.x >> 6);
  int lane = threadIdx.x & 63;
  if (e >= E_EDGES) return;
  int rel = et[e];
  int src = ei[e];
  int dst = ei[E_EDGES + e];
  const unsigned int* zs = (const unsigned int*)(Z + (size_t)src * 1536 + rel * 512);
  unsigned int* ad = (unsigned int*)(agg + (size_t)dst * 1536 + rel * 512);
  unsigned int v[4];
#pragma unroll
  for (int j = 0; j < 4; ++j) v[j] = zs[j * 64 + lane];
#pragma unroll
  for (int j = 0; j < 4; ++j) agg_atomic_add(ad + j * 64 + lane, v[j]);
}

// ---- fused relu, in place over Z: Z = relu(Z + agg + b1[col]) ----
__global__ void relu_all_kernel(unsigned short* __restrict__ Z,
                                const unsigned short* __restrict__ agg,
                                const float* __restrict__ b1) {  // [1536] flat
  int i = blockIdx.x * 256 + threadIdx.x;   // one thread = 8 cols (ushort8)
  if (i >= M_NODES * 192) return;
  int c = (i % 192) * 8;
  us8_t z = ((const us8_t*)Z)[i];
  us8_t a = ((const us8_t*)agg)[i];
  us8_t o;
#pragma unroll
  for (int j = 0; j < 8; ++j) {
    float v = bf2f((unsigned short)z[j]) + bf2f((unsigned short)a[j]) + b1[c + j];
    o[j] = f2bf(fmaxf(v, 0.f));
  }
  ((us8_t*)Z)[i] = o;
}

// ---------------- fused GEMM (R3-validated template, depth-1 dbuf) ----------
// C[M, NTC*128] = A[M,K](bf16) @ Bt[NTC*128, K]^T.
// MODE 1 (expand): col<512 -> outF[row*512+col] = acc + biasF[col] (f32)
//                  col>=512 -> outB[row*1536+col-512] = bf16(acc)   (no bias!)
// MODE 2 (reduce): outF[row*512+col] += acc + biasF[col]            (f32 RMW)
template <int NTC, int MODE>
__global__ __launch_bounds__(256) void gemm_kernel(
    const unsigned short* __restrict__ A,
    const unsigned short* __restrict__ Bt,
    int K,
    float* __restrict__ outF,
    unsigned short* __restrict__ outB,
    const float* __restrict__ biasF) {
  __shared__ alignas(16) unsigned short As[2][4096];  // [buf][kc][row][8]
  __shared__ alignas(16) unsigned short Bs[2][4096];
  const int tid  = threadIdx.x;
  const int lane = tid & 63;
  const int wid  = tid >> 6;
  const int wr   = wid >> 1;
  const int wc   = wid & 1;

  // T1: bijective XCD-chunked swizzle (m204), general form.
  constexpr int nwg = MT * NTC;
  constexpr int q   = nwg / 8;
  constexpr int rr  = nwg % 8;
  const int orig = blockIdx.x;
  const int xcd  = orig & 7;
  const int lid  = orig >> 3;
  const int swz  = (xcd < rr ? xcd * (q + 1) : rr * (q + 1) + (xcd - rr) * q) + lid;
  const int tileM = (swz / NTC) * 128;
  const int tileN = (swz % NTC) * 128;

  accum_t acc[4][4] = {};

  const int t0 = tid, t1 = tid + 256;
  const int kc0 = t0 >> 7, r0 = t0 & 127;
  const int kc1 = t1 >> 7, r1 = t1 & 127;
  int ar0 = tileM + r0; ar0 = ar0 < M_NODES ? ar0 : M_NODES - 1;
  int ar1 = tileM + r1; ar1 = ar1 < M_NODES ? ar1 : M_NODES - 1;
  const unsigned short* gA0 = A + (size_t)ar0 * K + kc0 * 8;
  const unsigned short* gA1 = A + (size_t)ar1 * K + kc1 * 8;
  const unsigned short* gB0 = Bt + (size_t)(tileN + r0) * K + kc0 * 8;
  const unsigned short* gB1 = Bt + (size_t)(tileN + r1) * K + kc1 * 8;

  const int kcl = lane >> 4;
  const int fr  = lane & 15;
  const unsigned short* pAf = &As[0][kcl * 1024 + (wr * 64 + fr) * 8];
  const unsigned short* pBf = &Bs[0][kcl * 1024 + (wc * 64 + fr) * 8];

#define STAGE(b, ks)                                  \
  do {                                                \
    const int koff_ = (ks) * 32;                      \
    gll16(gA0 + koff_, &As[(b)][t0 * 8]);             \
    gll16(gA1 + koff_, &As[(b)][t1 * 8]);             \
    gll16(gB0 + koff_, &Bs[(b)][t0 * 8]);             \
    gll16(gB1 + koff_, &Bs[(b)][t1 * 8]);             \
  } while (0)

  const int ksteps = K >> 5;
  STAGE(0, 0);
  for (int ks = 0; ks < ksteps; ++ks) {
    const int cur = ks & 1;
    if (ks + 1 < ksteps) {
      STAGE(cur ^ 1, ks + 1);                           // prefetch next tile
      asm volatile("s_waitcnt vmcnt(4)" ::: "memory");  // wait current only
    } else {
      asm volatile("s_waitcnt vmcnt(0)" ::: "memory");
    }
    __builtin_amdgcn_s_barrier();

    bfrag_t a[4], b[4];
    const unsigned short* pA = pAf + cur * 4096;
    const unsigned short* pB = pBf + cur * 4096;
#pragma unroll
    for (int m = 0; m < 4; ++m) a[m] = *(const bfrag_t*)(pA + m * 16 * 8);
#pragma unroll
    for (int n = 0; n < 4; ++n) b[n] = *(const bfrag_t*)(pB + n * 16 * 8);
    __builtin_amdgcn_s_setprio(1);
#pragma unroll
    for (int m = 0; m < 4; ++m)
#pragma unroll
      for (int n = 0; n < 4; ++n)
        acc[m][n] = __builtin_amdgcn_mfma_f32_16x16x32_bf16(a[m], b[n], acc[m][n], 0, 0, 0);
    __builtin_amdgcn_s_setprio(0);
    __builtin_amdgcn_s_barrier();
  }
#undef STAGE

  // epilogue: C row = (lane>>4)*4 + q, col = lane&15 (m89-verified layout)
  const int rq = lane >> 4;
#pragma unroll
  for (int n = 0; n < 4; ++n) {
    const int col = tileN + wc * 64 + n * 16 + fr;
    const float bv = (MODE == 2 || col < 512) ? biasF[col & 511] : 0.f;
#pragma unroll
    for (int m = 0; m < 4; ++m) {
      const int rbase = tileM + wr * 64 + m * 16 + rq * 4;
#pragma unroll
      for (int p = 0; p < 4; ++p) {
        const int row = rbase + p;
        if (row < M_NODES) {
          float v = acc[m][n][p] + bv;
          if (MODE == 1) {
            if (col < 512) outF[(size_t)row * 512 + col] = v;
            else           outB[(size_t)row * 1536 + (col - 512)] = f2bf(v);
          } else {
            outF[(size_t)row * 512 + col] += v;
          }
        }
      }
    }
  }
}

extern "C" void kernel_launch(void* const* d_in, const int* in_sizes, int n_in,
                              void* d_out, int out_size, void* d_ws, size_t ws_size,
                              hipStream_t stream) {
  const float* x     = (const float*)d_in[0];
  const int*   ei    = (const int*)d_in[1];
  const int*   et    = (const int*)d_in[2];
  const float* Wself = (const float*)d_in[3];
  const float* bself = (const float*)d_in[4];
  const float* W1    = (const float*)d_in[5];
  const float* b1    = (const float*)d_in[6];
  const float* W2    = (const float*)d_in[7];
  const float* b2    = (const float*)d_in[8];
  float* out = (float*)d_out;

  // ws layout (310.9 MB total, == R7's proven footprint):
  //   [0, 153.6 MB): agg bf16 [M,1536]  -- ALSO hosts xb bf16 [M,512] (51.2 MB)
  //                  during GEMM-1 only; agg memset happens after GEMM-1.
  //   [153.6, 307.2 MB): Z bf16 [M,1536]
  //   [307.2 MB +): Wt1, Wt2, bias2
  char* ws = (char*)d_ws;
  unsigned short* xb    = (unsigned short*)ws;                 // dead after GEMM-1
  unsigned short* agg   = (unsigned short*)ws;                 // live after GEMM-1
  unsigned short* Z     = (unsigned short*)(ws + 153600000);
  unsigned short* Wt1   = (unsigned short*)(ws + 307200000);   // 2.1 MB
  unsigned short* Wt2   = (unsigned short*)(ws + 309297152);   // 1.6 MB
  float*          bias2 = (float*)(ws + 310870016);            // 2 KB

  cast_w_kernel<<<7171, 256, 0, stream>>>(Wself, W1, W2, b2, Wt1, Wt2, bias2);
  cast_x_kernel<<<2048, 256, 0, stream>>>(x, xb, M_NODES * 512);

  // Y = x @ [W_self | W1_0 | W1_1 | W1_2] ; cols<512 -> out(f32)+b_self,
  // cols>=512 -> Z(bf16, NO b1: b1 must not enter the segment-sum)
  gemm_kernel<16, 1><<<MT * 16, 256, 0, stream>>>(xb, Wt1, 512, out, Z, bself);

  hipMemsetAsync(agg, 0, (size_t)M_NODES * 1536 * sizeof(unsigned short), stream);
  scatter_all_kernel<<<E_EDGES / 4, 256, 0, stream>>>(Z, ei, et, agg);
  relu_all_kernel<<<(M_NODES * 192 + 255) / 256, 256, 0, stream>>>(Z, agg, b1);

  // out += [h0|h1|h2] @ [W2_0; W2_1; W2_2] + bias2
  gemm_kernel<4, 2><<<MT * 4, 256, 0, stream>>>(Z, Wt2, 1536, out, nullptr, bias2);
}

// Round 9
// 789.901 us; speedup vs baseline: 1.9924x; 1.1215x over previous
//
#include <hip/hip_runtime.h>
#include <hip/hip_bf16.h>

typedef __attribute__((ext_vector_type(8))) short bfrag_t;   // 8 bf16 (4 VGPRs)
typedef __attribute__((ext_vector_type(4))) float accum_t;   // 4 f32
typedef __attribute__((ext_vector_type(8))) unsigned short us8_t;

static_assert(sizeof(bfrag_t) == 16, "frag size");

static constexpr int M_NODES = 50000;
static constexpr int E_EDGES = 156000;
static constexpr int MT256   = (M_NODES + 255) / 256;  // 196 M-tiles

// ---- manual RNE f32 -> bf16 ----
__device__ __forceinline__ unsigned short f2bf(float f) {
  unsigned int u = __float_as_uint(f);
  u = (u + 0x7FFFu + ((u >> 16) & 1u)) >> 16;
  return (unsigned short)u;
}
__device__ __forceinline__ float bf2f(unsigned short u) {
  return __uint_as_float(((unsigned int)u) << 16);
}

__device__ __forceinline__ void gll16(const unsigned short* g, unsigned short* l) {
  __builtin_amdgcn_global_load_lds(
      (const __attribute__((address_space(1))) void*)g,
      (__attribute__((address_space(3))) void*)l,
      16, 0, 0);
}

// ---- packed bf16x2 atomic add (HW instruction if available, CAS fallback) ----
typedef __attribute__((ext_vector_type(2))) short s2v;
__device__ __forceinline__ void agg_atomic_add(unsigned int* p, unsigned int zv) {
#if __has_builtin(__builtin_amdgcn_global_atomic_fadd_v2bf16)
  s2v v;
  __builtin_memcpy(&v, &zv, 4);
  __builtin_amdgcn_global_atomic_fadd_v2bf16(
      (__attribute__((address_space(1))) s2v*)p, v);
#else
  unsigned int old = *p, assumed;
  do {
    assumed = old;
    float lo = bf2f((unsigned short)(assumed & 0xffffu)) +
               bf2f((unsigned short)(zv & 0xffffu));
    float hi = bf2f((unsigned short)(assumed >> 16)) +
               bf2f((unsigned short)(zv >> 16));
    unsigned int nv = (unsigned int)f2bf(lo) | ((unsigned int)f2bf(hi) << 16);
    old = atomicCAS(p, assumed, nv);
  } while (old != assumed);
#endif
}

// ---- weight prep (unchanged, R7-validated) ----
__global__ void cast_w_kernel(const float* __restrict__ Wself,
                              const float* __restrict__ W1,
                              const float* __restrict__ W2,
                              const float* __restrict__ b2,
                              unsigned short* __restrict__ Wt1,
                              unsigned short* __restrict__ Wt2,
                              float* __restrict__ bias2) {
  int idx = blockIdx.x * 256 + threadIdx.x;
  if (idx < 1048576) {                       // Wt1
    int n = idx >> 9, k = idx & 511;
    float v = (n < 512)
        ? Wself[k * 512 + n]
        : W1[(size_t)((n - 512) >> 9) * 262144 + k * 512 + ((n - 512) & 511)];
    Wt1[idx] = f2bf(v);
  } else if (idx < 1835008) {                // Wt2 (j = n*1536 + kk)
    int j = idx - 1048576;
    int kk = j % 1536;
    int n  = j / 1536;
    Wt2[j] = f2bf(W2[(size_t)(kk >> 9) * 262144 + (size_t)(kk & 511) * 512 + n]);
  } else if (idx < 1835520) {                // bias2
    int c = idx - 1835008;
    bias2[c] = b2[c] + b2[512 + c] + b2[1024 + c];
  }
}

// ---- cast x (f32) -> xb (bf16), vectorized ----
__global__ void cast_x_kernel(const float* __restrict__ x,
                              unsigned short* __restrict__ xb, int n) {
  int stride = gridDim.x * blockDim.x;
  int n4 = n >> 2;
  for (int i = blockIdx.x * blockDim.x + threadIdx.x; i < n4; i += stride) {
    float4 v = ((const float4*)x)[i];
    ushort4 u;
    u.x = f2bf(v.x); u.y = f2bf(v.y); u.z = f2bf(v.z); u.w = f2bf(v.w);
    ((ushort4*)xb)[i] = u;
  }
}

// ---- fused scatter, all relations, packed bf16 atomics (R8-validated) ----
__global__ void scatter_all_kernel(const unsigned short* __restrict__ Z,
                                   const int* __restrict__ ei,
                                   const int* __restrict__ et,
                                   unsigned short* __restrict__ agg) {
  int e    = blockIdx.x * 4 + (threadIdx.x >> 6);
  int lane = threadIdx.x & 63;
  if (e >= E_EDGES) return;
  int rel = et[e];
  int src = ei[e];
  int dst = ei[E_EDGES + e];
  const unsigned int* zs = (const unsigned int*)(Z + (size_t)src * 1536 + rel * 512);
  unsigned int* ad = (unsigned int*)(agg + (size_t)dst * 1536 + rel * 512);
  unsigned int v[4];
#pragma unroll
  for (int j = 0; j < 4; ++j) v[j] = zs[j * 64 + lane];
#pragma unroll
  for (int j = 0; j < 4; ++j) agg_atomic_add(ad + j * 64 + lane, v[j]);
}

// ---- fused relu, in place over Z: Z = relu(Z + agg + b1[col]) ----
__global__ void relu_all_kernel(unsigned short* __restrict__ Z,
                                const unsigned short* __restrict__ agg,
                                const float* __restrict__ b1) {  // [1536] flat
  int i = blockIdx.x * 256 + threadIdx.x;   // one thread = 8 cols
  if (i >= M_NODES * 192) return;
  int c = (i % 192) * 8;
  us8_t z = ((const us8_t*)Z)[i];
  us8_t a = ((const us8_t*)agg)[i];
  us8_t o;
#pragma unroll
  for (int j = 0; j < 8; ++j) {
    float v = bf2f((unsigned short)z[j]) + bf2f((unsigned short)a[j]) + b1[c + j];
    o[j] = f2bf(fmaxf(v, 0.f));
  }
  ((us8_t*)Z)[i] = o;
}

// ============ 8-wave 256x256 GEMM, BK=64, fine-interleaved schedule =========
// 2 LDS buffers x 4 units {B.k0, A.k0, B.k1, A.k1} (16KB each, [kcl][row][8]
// layout -> conflict-free ds_read_b128). Per K-tile: 2 barriers; per k-slice:
// {8 ds_read | stage 1 unit | 16 MFMA | 4 ds_read | stage 1 unit | 16 MFMA}.
// Counted vmcnt(4) (= 2 units in flight) at every slice entry; vmcnt(0) only
// at the final slice. Staging targets the buffer NOT read this K-tile.
// MODE 1: col<512 -> f32 out + bias; col>=512 -> bf16 Z (no bias).
// MODE 2: f32 RMW accumulate + bias.
template <int NTC, int MODE, int KTOT>
__global__ __launch_bounds__(512) void gemm8w_kernel(
    const unsigned short* __restrict__ A,
    const unsigned short* __restrict__ Bt,
    float* __restrict__ outF,
    unsigned short* __restrict__ outB,
    const float* __restrict__ biasF) {
  constexpr int NT = KTOT / 64;
  __shared__ alignas(16) unsigned short L[2][32768];  // 128 KB
  const int tid  = threadIdx.x;
  const int lane = tid & 63;
  const int wid  = tid >> 6;   // 0..7
  const int wr   = wid >> 2;   // 0..1 : 128-row band
  const int wn   = wid & 3;    // 0..3 : 64-col band
  const int fr   = lane & 15;

  // T1: XCD-chunked swizzle (nwg % 8 == 0 for both instantiations)
  constexpr int nwg = MT256 * NTC;
  constexpr int q   = nwg / 8;
  const int orig = blockIdx.x;
  const int swz  = (orig & 7) * q + (orig >> 3);
  const int tileM = (swz / NTC) * 256;
  const int tileN = (swz % NTC) * 256;

  accum_t acc[8][4] = {};

  // ---- staging maps: thread t covers row (t&255), kcl halves {t>>8, t>>8+2}
  const int rowS = tid & 255;
  const int jk   = tid >> 8;   // 0/1
  int arow = tileM + rowS; arow = arow < M_NODES ? arow : M_NODES - 1;
  const unsigned short* gA = A  + (size_t)arow * KTOT + jk * 8;
  const unsigned short* gB = Bt + (size_t)(tileN + rowS) * KTOT + jk * 8;
  const int lB = (jk * 256 + rowS) * 8;          // u16 offset within B unit
  const int lA = 8192 + (jk * 256 + rowS) * 8;   // u16 offset within A unit

#define STG_B(buf, kt, ks) do {                                          \
    gll16(gB + (kt) * 64 + (ks) * 32 +  0, &L[buf][lB + (ks) * 16384]);  \
    gll16(gB + (kt) * 64 + (ks) * 32 + 16, &L[buf][lB + (ks) * 16384 + 4096]); \
  } while (0)
#define STG_A(buf, kt, ks) do {                                          \
    gll16(gA + (kt) * 64 + (ks) * 32 +  0, &L[buf][lA + (ks) * 16384]);  \
    gll16(gA + (kt) * 64 + (ks) * 32 + 16, &L[buf][lA + (ks) * 16384 + 4096]); \
  } while (0)

  // ---- fragment read offsets (u16): unit entry (kcl,row) at (kcl*256+row)*8
  const int kq8   = (lane >> 4) * 2048 + fr * 8;
  const int bbase = kq8 + wn * 512;            // + ks*16384 + nf*128
  const int abase = 8192 + kq8 + wr * 1024;    // + ks*16384 + mh*512 + mf*128

  // prologue: K-tile 0 fully staged into buf0, unit order U0,U1,U2,U3
  STG_B(0, 0, 0); STG_A(0, 0, 0); STG_B(0, 0, 1); STG_A(0, 0, 1);

  for (int kt = 0; kt < NT; ++kt) {
    const int X = kt & 1, Y = X ^ 1;
    const bool pf = (kt + 1 < NT);
#pragma unroll
    for (int ks = 0; ks < 2; ++ks) {
      // entry sync: this slice's units landed CU-wide (2 newer units may fly)
      if (ks == 1 && !pf) asm volatile("s_waitcnt vmcnt(0)" ::: "memory");
      else                asm volatile("s_waitcnt vmcnt(4)" ::: "memory");
      __builtin_amdgcn_s_barrier();
      asm volatile("" ::: "memory");

      bfrag_t b[4], a[4];
#pragma unroll
      for (int nf = 0; nf < 4; ++nf)
        b[nf] = *(const bfrag_t*)&L[X][ks * 16384 + bbase + nf * 128];
#pragma unroll
      for (int mf = 0; mf < 4; ++mf)
        a[mf] = *(const bfrag_t*)&L[X][ks * 16384 + abase + mf * 128];
      if (pf) STG_B(Y, kt + 1, ks);
      __builtin_amdgcn_s_setprio(1);
#pragma unroll
      for (int mf = 0; mf < 4; ++mf)
#pragma unroll
        for (int nf = 0; nf < 4; ++nf)
          acc[mf][nf] = __builtin_amdgcn_mfma_f32_16x16x32_bf16(a[mf], b[nf], acc[mf][nf], 0, 0, 0);
      __builtin_amdgcn_s_setprio(0);

      bfrag_t a2[4];
#pragma unroll
      for (int mf = 0; mf < 4; ++mf)
        a2[mf] = *(const bfrag_t*)&L[X][ks * 16384 + abase + 512 + mf * 128];
      if (pf) STG_A(Y, kt + 1, ks);
      __builtin_amdgcn_s_setprio(1);
#pragma unroll
      for (int mf = 0; mf < 4; ++mf)
#pragma unroll
        for (int nf = 0; nf < 4; ++nf)
          acc[4 + mf][nf] = __builtin_amdgcn_mfma_f32_16x16x32_bf16(a2[mf], b[nf], acc[4 + mf][nf], 0, 0, 0);
      __builtin_amdgcn_s_setprio(0);
    }
  }
#undef STG_A
#undef STG_B

  // epilogue: frag row = (lane>>4)*4 + p, col = lane&15 (m89-verified)
  const int rq = lane >> 4;
#pragma unroll
  for (int nf = 0; nf < 4; ++nf) {
    const int col = tileN + wn * 64 + nf * 16 + fr;
    const float bv = (MODE == 2 || col < 512) ? biasF[col & 511] : 0.f;
#pragma unroll
    for (int mf = 0; mf < 8; ++mf) {
      const int rbase = tileM + wr * 128 + mf * 16 + rq * 4;
#pragma unroll
      for (int p = 0; p < 4; ++p) {
        const int row = rbase + p;
        if (row < M_NODES) {
          float v = acc[mf][nf][p] + bv;
          if (MODE == 1) {
            if (col < 512) outF[(size_t)row * 512 + col] = v;
            else           outB[(size_t)row * 1536 + (col - 512)] = f2bf(v);
          } else {
            outF[(size_t)row * 512 + col] += v;
          }
        }
      }
    }
  }
}

extern "C" void kernel_launch(void* const* d_in, const int* in_sizes, int n_in,
                              void* d_out, int out_size, void* d_ws, size_t ws_size,
                              hipStream_t stream) {
  const float* x     = (const float*)d_in[0];
  const int*   ei    = (const int*)d_in[1];
  const int*   et    = (const int*)d_in[2];
  const float* Wself = (const float*)d_in[3];
  const float* bself = (const float*)d_in[4];
  const float* W1    = (const float*)d_in[5];
  const float* b1    = (const float*)d_in[6];
  const float* W2    = (const float*)d_in[7];
  const float* b2    = (const float*)d_in[8];
  float* out = (float*)d_out;

  // ws layout (310.9 MB, == R7/R8 proven footprint):
  //   [0, 153.6 MB): agg bf16 [M,1536] -- hosts xb bf16 [M,512] during GEMM-1
  //   [153.6, 307.2 MB): Z bf16 [M,1536]
  //   [307.2 MB +): Wt1, Wt2, bias2
  char* ws = (char*)d_ws;
  unsigned short* xb    = (unsigned short*)ws;
  unsigned short* agg   = (unsigned short*)ws;
  unsigned short* Z     = (unsigned short*)(ws + 153600000);
  unsigned short* Wt1   = (unsigned short*)(ws + 307200000);   // 2.1 MB
  unsigned short* Wt2   = (unsigned short*)(ws + 309297152);   // 1.6 MB
  float*          bias2 = (float*)(ws + 310870016);            // 2 KB

  cast_w_kernel<<<7171, 256, 0, stream>>>(Wself, W1, W2, b2, Wt1, Wt2, bias2);
  cast_x_kernel<<<2048, 256, 0, stream>>>(x, xb, M_NODES * 512);

  // G1: Y = x @ [W_self | W1_0 | W1_1 | W1_2]  (M=50000, N=2048, K=512)
  gemm8w_kernel<8, 1, 512><<<MT256 * 8, 512, 0, stream>>>(xb, Wt1, out, Z, bself);

  hipMemsetAsync(agg, 0, (size_t)M_NODES * 1536 * sizeof(unsigned short), stream);
  scatter_all_kernel<<<E_EDGES / 4, 256, 0, stream>>>(Z, ei, et, agg);
  relu_all_kernel<<<(M_NODES * 192 + 255) / 256, 256, 0, stream>>>(Z, agg, b1);

  // G2: out += [h0|h1|h2] @ [W2_0; W2_1; W2_2] + bias2  (N=512, K=1536)
  gemm8w_kernel<2, 2, 1536><<<MT256 * 2, 512, 0, stream>>>(Z, Wt2, out, nullptr, bias2);
}